// Round 2
// baseline (177.790 us; speedup 1.0000x reference)
//
#include <hip/hip_runtime.h>

#define D 64

// ---------------------------------------------------------------------------
// Kernel 1 (fused): blocks [0, nGemmBlocks) compute support = x @ W;
// blocks [nGemmBlocks, ...) build the CSR row_ptr from sorted edge_row.
//
// GEMM part: 256 threads cover 64 rows. W (16KB) + x-tile (16KB) in LDS.
// Each thread computes a 4-row x 4-col register block.
// x-tile is quad-swizzled: element (r,k) lives at xs[r*64 + (k ^ M(r))],
// M(r) = ((r>>2)&3)<<2.  Staging writes stay contiguous b128; the 4
// same-k reads per thread hit 4 distinct banks (16-lane broadcast each).
// ---------------------------------------------------------------------------
__global__ __launch_bounds__(256) void gemm_and_rowptr(
    const float* __restrict__ x, const float* __restrict__ w,
    float* __restrict__ sup, int N,
    const int* __restrict__ erow, int* __restrict__ rptr, int E,
    int nGemmBlocks) {
  if ((int)blockIdx.x >= nGemmBlocks) {
    // ---- row_ptr part: rptr[q] = first edge index with row >= q ----
    const int e = (blockIdx.x - nGemmBlocks) * 256 + threadIdx.x;
    if (e < E) {
      const int r = erow[e];
      const int rprev = (e == 0) ? -1 : erow[e - 1];
      for (int q = rprev + 1; q <= r; ++q) rptr[q] = e;
      if (e == E - 1) {
        for (int q = r + 1; q <= N; ++q) rptr[q] = E;
      }
    }
    return;
  }

  // ---- GEMM part ----
  __shared__ alignas(16) float ws[D * D];   // 16 KB
  __shared__ alignas(16) float xs[64 * D];  // 16 KB (quad-swizzled)
  const int tid = threadIdx.x;
  const int rowBase = blockIdx.x * 64;

  // Stage W: 4096 floats, float4-coalesced, linear.
#pragma unroll
  for (int i = 0; i < 4; ++i) {
    const int idx = i * 1024 + tid * 4;
    *(float4*)&ws[idx] = *(const float4*)&w[idx];
  }
  // Stage x tile (64 rows), one swizzled b128 write per thread per iter.
#pragma unroll
  for (int i = 0; i < 4; ++i) {
    const int idx = i * 1024 + tid * 4;
    const int rl = idx >> 6;  // local row 0..63
    const int c = idx & 63;   // col (multiple of 4)
    const int r = rowBase + rl;
    float4 v = make_float4(0.f, 0.f, 0.f, 0.f);
    if (r < N) v = *(const float4*)&x[(size_t)r * D + c];
    const int M = ((rl >> 2) & 3) << 2;
    *(float4*)&xs[rl * D + (c ^ M)] = v;
  }
  __syncthreads();

  const int jg = tid & 15;          // column group: cols jg*4 .. jg*4+3
  const int lr0 = (tid >> 4) << 2;  // local row base: 4 consecutive rows
  const int M = ((tid >> 4) & 3) << 2;  // swizzle key, same for all 4 rows

  float4 A0 = make_float4(0.f, 0.f, 0.f, 0.f);
  float4 A1 = A0, A2 = A0, A3 = A0;

#pragma unroll
  for (int k = 0; k < D; ++k) {
    const float4 wv = *(const float4*)&ws[k * D + (jg << 2)];
    const int kk = k ^ M;
    const float x0 = xs[(lr0 + 0) * D + kk];
    const float x1 = xs[(lr0 + 1) * D + kk];
    const float x2 = xs[(lr0 + 2) * D + kk];
    const float x3 = xs[(lr0 + 3) * D + kk];
    A0.x = fmaf(wv.x, x0, A0.x); A0.y = fmaf(wv.y, x0, A0.y);
    A0.z = fmaf(wv.z, x0, A0.z); A0.w = fmaf(wv.w, x0, A0.w);
    A1.x = fmaf(wv.x, x1, A1.x); A1.y = fmaf(wv.y, x1, A1.y);
    A1.z = fmaf(wv.z, x1, A1.z); A1.w = fmaf(wv.w, x1, A1.w);
    A2.x = fmaf(wv.x, x2, A2.x); A2.y = fmaf(wv.y, x2, A2.y);
    A2.z = fmaf(wv.z, x2, A2.z); A2.w = fmaf(wv.w, x2, A2.w);
    A3.x = fmaf(wv.x, x3, A3.x); A3.y = fmaf(wv.y, x3, A3.y);
    A3.z = fmaf(wv.z, x3, A3.z); A3.w = fmaf(wv.w, x3, A3.w);
  }

  const int cb = jg << 2;
  int r = rowBase + lr0 + 0;
  if (r < N) *(float4*)&sup[(size_t)r * D + cb] = A0;
  r = rowBase + lr0 + 1;
  if (r < N) *(float4*)&sup[(size_t)r * D + cb] = A1;
  r = rowBase + lr0 + 2;
  if (r < N) *(float4*)&sup[(size_t)r * D + cb] = A2;
  r = rowBase + lr0 + 3;
  if (r < N) *(float4*)&sup[(size_t)r * D + cb] = A3;
}

// ---------------------------------------------------------------------------
// Kernel 2: out[r,:] = relu( sum_{e in row r} edge_val[e] * support[col[e],:] )
// One wave per row, lane = output column. Scalar (SGPR) loop control via
// readfirstlane; 4 independent coalesced 256B gathers in flight; no atomics;
// ReLU fused into the store.
// ---------------------------------------------------------------------------
__global__ __launch_bounds__(256) void spmm_relu(const float* __restrict__ sup,
                                                 const int* __restrict__ rp,
                                                 const int* __restrict__ col,
                                                 const float* __restrict__ val,
                                                 float* __restrict__ out, int N) {
  const int lane = threadIdx.x & 63;
  const int r = blockIdx.x * 4 + (threadIdx.x >> 6);
  if (r >= N) return;
  const int s = __builtin_amdgcn_readfirstlane(rp[r]);
  const int e = __builtin_amdgcn_readfirstlane(rp[r + 1]);
  float acc = 0.f;
  int i = s;
  for (; i + 4 <= e; i += 4) {
    const int c0 = col[i];
    const int c1 = col[i + 1];
    const int c2 = col[i + 2];
    const int c3 = col[i + 3];
    const float v0 = val[i];
    const float v1 = val[i + 1];
    const float v2 = val[i + 2];
    const float v3 = val[i + 3];
    const float g0 = sup[(size_t)c0 * D + lane];
    const float g1 = sup[(size_t)c1 * D + lane];
    const float g2 = sup[(size_t)c2 * D + lane];
    const float g3 = sup[(size_t)c3 * D + lane];
    acc = fmaf(g0, v0, acc);
    acc = fmaf(g1, v1, acc);
    acc = fmaf(g2, v2, acc);
    acc = fmaf(g3, v3, acc);
  }
  for (; i < e; ++i) {
    acc = fmaf(sup[(size_t)col[i] * D + lane], val[i], acc);
  }
  out[(size_t)r * D + lane] = fmaxf(acc, 0.f);
}

// ---------------------------------------------------------------------------
extern "C" void kernel_launch(void* const* d_in, const int* in_sizes, int n_in,
                              void* d_out, int out_size, void* d_ws, size_t ws_size,
                              hipStream_t stream) {
  const float* x = (const float*)d_in[0];
  const float* w = (const float*)d_in[1];
  const int* erow = (const int*)d_in[2];
  const int* ecol = (const int*)d_in[3];
  const float* eval = (const float*)d_in[4];
  float* out = (float*)d_out;

  const int N = in_sizes[0] / D;  // 100000
  const int E = in_sizes[2];      // 1200000

  float* sup = (float*)d_ws;                                      // N*64 f32 = 25.6 MB
  int* rp = (int*)((char*)d_ws + (size_t)N * D * sizeof(float));  // N+1 ints

  const int nGemmBlocks = (N + 63) / 64;
  const int nRpBlocks = (E + 255) / 256;

  gemm_and_rowptr<<<nGemmBlocks + nRpBlocks, 256, 0, stream>>>(
      x, w, sup, N, erow, rp, E, nGemmBlocks);
  spmm_relu<<<(N + 3) / 4, 256, 0, stream>>>(sup, rp, ecol, eval, out, N);
}

// Round 3
// 140.128 us; speedup vs baseline: 1.2688x; 1.2688x over previous
//
#include <hip/hip_runtime.h>
#include <hip/hip_fp16.h>

#define D 64

// ---------------------------------------------------------------------------
// Kernel 1 (fused): blocks [0, nGemmBlocks) compute support = x @ W (fp16 out);
// blocks [nGemmBlocks, ...) build CSR row_ptr from sorted edge_row.
//
// GEMM: 256 threads / 128 rows per block. W (16KB) + x-tile (32KB) in LDS.
// Thread (rg=tid>>3, cg=tid&7) computes rows rg*4..+3 x cols cg*8..+7:
// per k: 2 ds_read_b128 (W) + 4 ds_read_b32 (x) + 32 FMA  -> VALU-bound.
// x-tile swizzle: element (r,k) at xs[r*64 + (k ^ M(r))], M(r)=((r>>2)&15)<<2.
// Staging writes stay contiguous b128; reads are conflict-free (8 rowgroups
// per wave hit 8 distinct banks; same-rg lanes broadcast).
// ---------------------------------------------------------------------------
__global__ __launch_bounds__(256, 3) void gemm_and_rowptr(
    const float* __restrict__ x, const float* __restrict__ w,
    __half* __restrict__ sup, int N,
    const int* __restrict__ erow, int* __restrict__ rptr, int E,
    int nGemmBlocks) {
  if ((int)blockIdx.x >= nGemmBlocks) {
    // ---- row_ptr: rptr[q] = first edge index with row >= q; rptr[N] = E ----
    const int e = (blockIdx.x - nGemmBlocks) * 256 + threadIdx.x;
    if (e < E) {
      const int r = erow[e];
      const int rprev = (e == 0) ? -1 : erow[e - 1];
      for (int q = rprev + 1; q <= r; ++q) rptr[q] = e;
      if (e == E - 1)
        for (int q = r + 1; q <= N; ++q) rptr[q] = E;
    }
    return;
  }

  __shared__ alignas(16) float ws[D * D];    // 16 KB
  __shared__ alignas(16) float xs[128 * D];  // 32 KB (swizzled)
  const int tid = threadIdx.x;
  const int rowBase = blockIdx.x * 128;

  // Stage W: 4096 floats, float4-coalesced, linear.
#pragma unroll
  for (int i = 0; i < 4; ++i) {
    const int idx = i * 1024 + tid * 4;
    *(float4*)&ws[idx] = *(const float4*)&w[idx];
  }
  // Stage x tile (128 rows), one swizzled b128 write per thread per iter.
#pragma unroll
  for (int i = 0; i < 8; ++i) {
    const int idx = i * 1024 + tid * 4;
    const int rl = idx >> 6;  // local row 0..127
    const int c = idx & 63;   // col (multiple of 4)
    const int r = rowBase + rl;
    float4 v = make_float4(0.f, 0.f, 0.f, 0.f);
    if (r < N) v = *(const float4*)&x[(size_t)r * D + c];
    const int M = ((rl >> 2) & 15) << 2;
    *(float4*)&xs[rl * D + (c ^ M)] = v;
  }
  __syncthreads();

  const int cg = tid & 7;   // col group: cols cg*8 .. cg*8+7
  const int rg = tid >> 3;  // row group: rows rg*4 .. rg*4+3 (0..31)
  const int M = (rg & 15) << 2;
  const int cb = cg << 3;

  float4 A00 = make_float4(0.f, 0.f, 0.f, 0.f), A01 = A00;
  float4 A10 = A00, A11 = A00, A20 = A00, A21 = A00, A30 = A00, A31 = A00;

#pragma unroll 4
  for (int k = 0; k < D; ++k) {
    const float4 w0 = *(const float4*)&ws[k * D + cb];
    const float4 w1 = *(const float4*)&ws[k * D + cb + 4];
    const int kk = k ^ M;
    const float x0 = xs[(rg * 4 + 0) * D + kk];
    const float x1 = xs[(rg * 4 + 1) * D + kk];
    const float x2 = xs[(rg * 4 + 2) * D + kk];
    const float x3 = xs[(rg * 4 + 3) * D + kk];
    A00.x = fmaf(w0.x, x0, A00.x); A00.y = fmaf(w0.y, x0, A00.y);
    A00.z = fmaf(w0.z, x0, A00.z); A00.w = fmaf(w0.w, x0, A00.w);
    A01.x = fmaf(w1.x, x0, A01.x); A01.y = fmaf(w1.y, x0, A01.y);
    A01.z = fmaf(w1.z, x0, A01.z); A01.w = fmaf(w1.w, x0, A01.w);
    A10.x = fmaf(w0.x, x1, A10.x); A10.y = fmaf(w0.y, x1, A10.y);
    A10.z = fmaf(w0.z, x1, A10.z); A10.w = fmaf(w0.w, x1, A10.w);
    A11.x = fmaf(w1.x, x1, A11.x); A11.y = fmaf(w1.y, x1, A11.y);
    A11.z = fmaf(w1.z, x1, A11.z); A11.w = fmaf(w1.w, x1, A11.w);
    A20.x = fmaf(w0.x, x2, A20.x); A20.y = fmaf(w0.y, x2, A20.y);
    A20.z = fmaf(w0.z, x2, A20.z); A20.w = fmaf(w0.w, x2, A20.w);
    A21.x = fmaf(w1.x, x2, A21.x); A21.y = fmaf(w1.y, x2, A21.y);
    A21.z = fmaf(w1.z, x2, A21.z); A21.w = fmaf(w1.w, x2, A21.w);
    A30.x = fmaf(w0.x, x3, A30.x); A30.y = fmaf(w0.y, x3, A30.y);
    A30.z = fmaf(w0.z, x3, A30.z); A30.w = fmaf(w0.w, x3, A30.w);
    A31.x = fmaf(w1.x, x3, A31.x); A31.y = fmaf(w1.y, x3, A31.y);
    A31.z = fmaf(w1.z, x3, A31.z); A31.w = fmaf(w1.w, x3, A31.w);
  }

#define STORE_ROW(i, L, R)                                          \
  {                                                                 \
    const int r = rowBase + rg * 4 + (i);                           \
    if (r < N) {                                                    \
      __half2 h[4];                                                 \
      h[0] = __floats2half2_rn((L).x, (L).y);                       \
      h[1] = __floats2half2_rn((L).z, (L).w);                       \
      h[2] = __floats2half2_rn((R).x, (R).y);                       \
      h[3] = __floats2half2_rn((R).z, (R).w);                       \
      *(float4*)&sup[(size_t)r * D + cb] = *(float4*)h;             \
    }                                                               \
  }
  STORE_ROW(0, A00, A01)
  STORE_ROW(1, A10, A11)
  STORE_ROW(2, A20, A21)
  STORE_ROW(3, A30, A31)
#undef STORE_ROW
}

// ---------------------------------------------------------------------------
// Kernel 2: out[r,:] = relu( sum_{e in row r} val[e] * sup[col[e],:] )
// One wave per row; each half-wave handles one edge of a pair (g=lane>>5),
// lane covers a half2 (2 cols, 4B). 8 edges in flight; shfl_xor(32) combine;
// coalesced float2 store with fused ReLU. No atomics.
// ---------------------------------------------------------------------------
__global__ __launch_bounds__(256) void spmm_relu(
    const __half2* __restrict__ sup, const int* __restrict__ rp,
    const int* __restrict__ col, const float* __restrict__ val,
    float* __restrict__ out, int N) {
  const int lane = threadIdx.x & 63;
  const int g = lane >> 5;   // edge-of-pair selector
  const int lp = lane & 31;  // col-pair index (cols 2*lp, 2*lp+1)
  const int r = blockIdx.x * 4 + (threadIdx.x >> 6);
  if (r >= N) return;
  const int s = __builtin_amdgcn_readfirstlane(rp[r]);
  const int e = __builtin_amdgcn_readfirstlane(rp[r + 1]);
  float ax = 0.f, ay = 0.f;
  int i = s;
  for (; i + 8 <= e; i += 8) {
#pragma unroll
    for (int u = 0; u < 4; ++u) {
      const int idx = i + 2 * u + g;
      const int c = col[idx];
      const float v = val[idx];
      const float2 f = __half22float2(sup[(size_t)c * 32 + lp]);
      ax = fmaf(f.x, v, ax);
      ay = fmaf(f.y, v, ay);
    }
  }
  for (; i + 2 <= e; i += 2) {
    const int idx = i + g;
    const int c = col[idx];
    const float v = val[idx];
    const float2 f = __half22float2(sup[(size_t)c * 32 + lp]);
    ax = fmaf(f.x, v, ax);
    ay = fmaf(f.y, v, ay);
  }
  if (i < e && g == 0) {
    const int c = col[i];
    const float v = val[i];
    const float2 f = __half22float2(sup[(size_t)c * 32 + lp]);
    ax = fmaf(f.x, v, ax);
    ay = fmaf(f.y, v, ay);
  }
  ax += __shfl_xor(ax, 32);
  ay += __shfl_xor(ay, 32);
  if (g == 0) {
    float2 o;
    o.x = fmaxf(ax, 0.f);
    o.y = fmaxf(ay, 0.f);
    *(float2*)&out[(size_t)r * D + lp * 2] = o;
  }
}

// ---------------------------------------------------------------------------
extern "C" void kernel_launch(void* const* d_in, const int* in_sizes, int n_in,
                              void* d_out, int out_size, void* d_ws, size_t ws_size,
                              hipStream_t stream) {
  const float* x = (const float*)d_in[0];
  const float* w = (const float*)d_in[1];
  const int* erow = (const int*)d_in[2];
  const int* ecol = (const int*)d_in[3];
  const float* eval = (const float*)d_in[4];
  float* out = (float*)d_out;

  const int N = in_sizes[0] / D;  // 100000
  const int E = in_sizes[2];      // 1200000

  __half* sup = (__half*)d_ws;  // N*64 fp16 = 12.8 MB
  int* rp = (int*)((char*)d_ws + (((size_t)N * D * sizeof(__half) + 255) & ~(size_t)255));

  const int nGemmBlocks = (N + 127) / 128;
  const int nRpBlocks = (E + 255) / 256;

  gemm_and_rowptr<<<nGemmBlocks + nRpBlocks, 256, 0, stream>>>(
      x, w, sup, N, erow, rp, E, nGemmBlocks);
  spmm_relu<<<(N + 3) / 4, 256, 0, stream>>>((const __half2*)sup, rp, ecol, eval,
                                             out, N);
}

// Round 4
// 133.112 us; speedup vs baseline: 1.3356x; 1.0527x over previous
//
#include <hip/hip_runtime.h>
#include <hip/hip_fp16.h>

#define D 64

// ---------------------------------------------------------------------------
// Kernel 1 (fused): blocks [0, nGemmBlocks) compute support = x @ W (fp16 out);
// blocks [nGemmBlocks, ...) build CSR row_ptr from sorted edge_row.
// (unchanged from round 3 — clean A/B on the spmm rewrite)
// ---------------------------------------------------------------------------
__global__ __launch_bounds__(256, 3) void gemm_and_rowptr(
    const float* __restrict__ x, const float* __restrict__ w,
    __half* __restrict__ sup, int N,
    const int* __restrict__ erow, int* __restrict__ rptr, int E,
    int nGemmBlocks) {
  if ((int)blockIdx.x >= nGemmBlocks) {
    const int e = (blockIdx.x - nGemmBlocks) * 256 + threadIdx.x;
    if (e < E) {
      const int r = erow[e];
      const int rprev = (e == 0) ? -1 : erow[e - 1];
      for (int q = rprev + 1; q <= r; ++q) rptr[q] = e;
      if (e == E - 1)
        for (int q = r + 1; q <= N; ++q) rptr[q] = E;
    }
    return;
  }

  __shared__ alignas(16) float ws[D * D];    // 16 KB
  __shared__ alignas(16) float xs[128 * D];  // 32 KB (swizzled)
  const int tid = threadIdx.x;
  const int rowBase = blockIdx.x * 128;

#pragma unroll
  for (int i = 0; i < 4; ++i) {
    const int idx = i * 1024 + tid * 4;
    *(float4*)&ws[idx] = *(const float4*)&w[idx];
  }
#pragma unroll
  for (int i = 0; i < 8; ++i) {
    const int idx = i * 1024 + tid * 4;
    const int rl = idx >> 6;
    const int c = idx & 63;
    const int r = rowBase + rl;
    float4 v = make_float4(0.f, 0.f, 0.f, 0.f);
    if (r < N) v = *(const float4*)&x[(size_t)r * D + c];
    const int M = ((rl >> 2) & 15) << 2;
    *(float4*)&xs[rl * D + (c ^ M)] = v;
  }
  __syncthreads();

  const int cg = tid & 7;
  const int rg = tid >> 3;
  const int M = (rg & 15) << 2;
  const int cb = cg << 3;

  float4 A00 = make_float4(0.f, 0.f, 0.f, 0.f), A01 = A00;
  float4 A10 = A00, A11 = A00, A20 = A00, A21 = A00, A30 = A00, A31 = A00;

#pragma unroll 4
  for (int k = 0; k < D; ++k) {
    const float4 w0 = *(const float4*)&ws[k * D + cb];
    const float4 w1 = *(const float4*)&ws[k * D + cb + 4];
    const int kk = k ^ M;
    const float x0 = xs[(rg * 4 + 0) * D + kk];
    const float x1 = xs[(rg * 4 + 1) * D + kk];
    const float x2 = xs[(rg * 4 + 2) * D + kk];
    const float x3 = xs[(rg * 4 + 3) * D + kk];
    A00.x = fmaf(w0.x, x0, A00.x); A00.y = fmaf(w0.y, x0, A00.y);
    A00.z = fmaf(w0.z, x0, A00.z); A00.w = fmaf(w0.w, x0, A00.w);
    A01.x = fmaf(w1.x, x0, A01.x); A01.y = fmaf(w1.y, x0, A01.y);
    A01.z = fmaf(w1.z, x0, A01.z); A01.w = fmaf(w1.w, x0, A01.w);
    A10.x = fmaf(w0.x, x1, A10.x); A10.y = fmaf(w0.y, x1, A10.y);
    A10.z = fmaf(w0.z, x1, A10.z); A10.w = fmaf(w0.w, x1, A10.w);
    A11.x = fmaf(w1.x, x1, A11.x); A11.y = fmaf(w1.y, x1, A11.y);
    A11.z = fmaf(w1.z, x1, A11.z); A11.w = fmaf(w1.w, x1, A11.w);
    A20.x = fmaf(w0.x, x2, A20.x); A20.y = fmaf(w0.y, x2, A20.y);
    A20.z = fmaf(w0.z, x2, A20.z); A20.w = fmaf(w0.w, x2, A20.w);
    A21.x = fmaf(w1.x, x2, A21.x); A21.y = fmaf(w1.y, x2, A21.y);
    A21.z = fmaf(w1.z, x2, A21.z); A21.w = fmaf(w1.w, x2, A21.w);
    A30.x = fmaf(w0.x, x3, A30.x); A30.y = fmaf(w0.y, x3, A30.y);
    A30.z = fmaf(w0.z, x3, A30.z); A30.w = fmaf(w0.w, x3, A30.w);
    A31.x = fmaf(w1.x, x3, A31.x); A31.y = fmaf(w1.y, x3, A31.y);
    A31.z = fmaf(w1.z, x3, A31.z); A31.w = fmaf(w1.w, x3, A31.w);
  }

#define STORE_ROW(i, L, R)                                          \
  {                                                                 \
    const int r = rowBase + rg * 4 + (i);                           \
    if (r < N) {                                                    \
      __half2 h[4];                                                 \
      h[0] = __floats2half2_rn((L).x, (L).y);                       \
      h[1] = __floats2half2_rn((L).z, (L).w);                       \
      h[2] = __floats2half2_rn((R).x, (R).y);                       \
      h[3] = __floats2half2_rn((R).z, (R).w);                       \
      *(float4*)&sup[(size_t)r * D + cb] = *(float4*)h;             \
    }                                                               \
  }
  STORE_ROW(0, A00, A01)
  STORE_ROW(1, A10, A11)
  STORE_ROW(2, A20, A21)
  STORE_ROW(3, A30, A31)
#undef STORE_ROW
}

// ---------------------------------------------------------------------------
// Kernel 2: out[r,:] = relu( sum_{e in row r} val[e] * sup[col[e],:] )
// One wave per row. Lane-parallel prefetch of the row's first 64 col/val
// (one coalesced 256B load), then __shfl broadcast — no per-edge metadata
// latency. 8 lanes per edge, float4 (16B, 8 fp16 cols) gathers: 8 edges per
// gather instruction, zero-padded to 16 slots so an avg-degree row issues ALL
// its gathers before the first waitcnt (~2 serialized latencies per row).
// 3-level shfl_xor combine; lanes 0-7 store with fused ReLU.
// ---------------------------------------------------------------------------
__global__ __launch_bounds__(256) void spmm_relu(
    const float4* __restrict__ sup4,  // fp16 rows: 8 float4 per row
    const int* __restrict__ rp, const int* __restrict__ col,
    const float* __restrict__ val, float* __restrict__ out, int N) {
  const int lane = threadIdx.x & 63;
  const int g = lane >> 3;  // edge slot within a chunk (0..7)
  const int lg = lane & 7;  // column slice: cols 8*lg .. 8*lg+7
  const int r = blockIdx.x * 4 + (threadIdx.x >> 6);
  if (r >= N) return;
  const int s = __builtin_amdgcn_readfirstlane(rp[r]);
  const int e = __builtin_amdgcn_readfirstlane(rp[r + 1]);
  const int deg = e - s;

  // Lane-parallel prefetch of first 64 edges' metadata (coalesced).
  int myc = 0;
  float myv = 0.f;
  if (lane < deg) {
    myc = col[s + lane];
    myv = val[s + lane];
  }

  float a0 = 0.f, a1 = 0.f, a2 = 0.f, a3 = 0.f;
  float a4 = 0.f, a5 = 0.f, a6 = 0.f, a7 = 0.f;

#define ACCUM(Q, V)                                                  \
  {                                                                  \
    const __half2* h = (const __half2*)&(Q);                         \
    const float2 f0 = __half22float2(h[0]);                          \
    const float2 f1 = __half22float2(h[1]);                          \
    const float2 f2 = __half22float2(h[2]);                          \
    const float2 f3 = __half22float2(h[3]);                          \
    a0 = fmaf(f0.x, (V), a0); a1 = fmaf(f0.y, (V), a1);              \
    a2 = fmaf(f1.x, (V), a2); a3 = fmaf(f1.y, (V), a3);              \
    a4 = fmaf(f2.x, (V), a4); a5 = fmaf(f2.y, (V), a5);              \
    a6 = fmaf(f3.x, (V), a6); a7 = fmaf(f3.y, (V), a7);              \
  }

  const int K = deg < 64 ? deg : 64;
  for (int jb = 0; jb < K; jb += 16) {
    const int j0 = jb + g;
    const int j1 = jb + 8 + g;
    int c0 = __shfl(myc, j0);
    float v0 = __shfl(myv, j0);
    int c1 = __shfl(myc, j1);
    float v1 = __shfl(myv, j1);
    if (j0 >= K) { c0 = 0; v0 = 0.f; }  // zero-pad: row 0 is L2-hot, v=0
    if (j1 >= K) { c1 = 0; v1 = 0.f; }
    const float4 q0 = sup4[(size_t)c0 * 8 + lg];
    const float4 q1 = sup4[(size_t)c1 * 8 + lg];
    ACCUM(q0, v0)
    ACCUM(q1, v1)
  }
  // Rare high-degree tail (deg > 64): direct predicated loads.
  for (int j = 64; j < deg; j += 8) {
    int c = 0;
    float v = 0.f;
    if (j + g < deg) {
      c = col[s + j + g];
      v = val[s + j + g];
    }
    const float4 q = sup4[(size_t)c * 8 + lg];
    ACCUM(q, v)
  }
#undef ACCUM

  // Reduce across the 8 edge slots (lane bits 3..5).
#define RED(x)            \
  x += __shfl_xor(x, 8);  \
  x += __shfl_xor(x, 16); \
  x += __shfl_xor(x, 32);
  RED(a0) RED(a1) RED(a2) RED(a3) RED(a4) RED(a5) RED(a6) RED(a7)
#undef RED

  if (g == 0) {  // lanes 0-7 each store 8 floats (two float4)
    float4 o0, o1;
    o0.x = fmaxf(a0, 0.f); o0.y = fmaxf(a1, 0.f);
    o0.z = fmaxf(a2, 0.f); o0.w = fmaxf(a3, 0.f);
    o1.x = fmaxf(a4, 0.f); o1.y = fmaxf(a5, 0.f);
    o1.z = fmaxf(a6, 0.f); o1.w = fmaxf(a7, 0.f);
    float* po = &out[(size_t)r * D + lg * 8];
    *(float4*)po = o0;
    *(float4*)(po + 4) = o1;
  }
}

// ---------------------------------------------------------------------------
extern "C" void kernel_launch(void* const* d_in, const int* in_sizes, int n_in,
                              void* d_out, int out_size, void* d_ws, size_t ws_size,
                              hipStream_t stream) {
  const float* x = (const float*)d_in[0];
  const float* w = (const float*)d_in[1];
  const int* erow = (const int*)d_in[2];
  const int* ecol = (const int*)d_in[3];
  const float* eval = (const float*)d_in[4];
  float* out = (float*)d_out;

  const int N = in_sizes[0] / D;  // 100000
  const int E = in_sizes[2];      // 1200000

  __half* sup = (__half*)d_ws;  // N*64 fp16 = 12.8 MB
  int* rp = (int*)((char*)d_ws + (((size_t)N * D * sizeof(__half) + 255) & ~(size_t)255));

  const int nGemmBlocks = (N + 127) / 128;
  const int nRpBlocks = (E + 255) / 256;

  gemm_and_rowptr<<<nGemmBlocks + nRpBlocks, 256, 0, stream>>>(
      x, w, sup, N, erow, rp, E, nGemmBlocks);
  spmm_relu<<<(N + 3) / 4, 256, 0, stream>>>((const float4*)sup, rp, ecol, eval,
                                             out, N);
}

// Round 5
// 132.926 us; speedup vs baseline: 1.3375x; 1.0014x over previous
//
#include <hip/hip_runtime.h>
#include <hip/hip_fp16.h>

#define D 64

// ---------------------------------------------------------------------------
// Kernel 1 (fused): blocks [0, nGemmBlocks) compute support = x @ W (fp16 out);
// blocks [nGemmBlocks, ...) build CSR row_ptr from sorted edge_row.
// (unchanged from rounds 3/4 — clean A/B on the spmm pipeline change)
// ---------------------------------------------------------------------------
__global__ __launch_bounds__(256, 3) void gemm_and_rowptr(
    const float* __restrict__ x, const float* __restrict__ w,
    __half* __restrict__ sup, int N,
    const int* __restrict__ erow, int* __restrict__ rptr, int E,
    int nGemmBlocks) {
  if ((int)blockIdx.x >= nGemmBlocks) {
    const int e = (blockIdx.x - nGemmBlocks) * 256 + threadIdx.x;
    if (e < E) {
      const int r = erow[e];
      const int rprev = (e == 0) ? -1 : erow[e - 1];
      for (int q = rprev + 1; q <= r; ++q) rptr[q] = e;
      if (e == E - 1)
        for (int q = r + 1; q <= N; ++q) rptr[q] = E;
    }
    return;
  }

  __shared__ alignas(16) float ws[D * D];    // 16 KB
  __shared__ alignas(16) float xs[128 * D];  // 32 KB (swizzled)
  const int tid = threadIdx.x;
  const int rowBase = blockIdx.x * 128;

#pragma unroll
  for (int i = 0; i < 4; ++i) {
    const int idx = i * 1024 + tid * 4;
    *(float4*)&ws[idx] = *(const float4*)&w[idx];
  }
#pragma unroll
  for (int i = 0; i < 8; ++i) {
    const int idx = i * 1024 + tid * 4;
    const int rl = idx >> 6;
    const int c = idx & 63;
    const int r = rowBase + rl;
    float4 v = make_float4(0.f, 0.f, 0.f, 0.f);
    if (r < N) v = *(const float4*)&x[(size_t)r * D + c];
    const int M = ((rl >> 2) & 15) << 2;
    *(float4*)&xs[rl * D + (c ^ M)] = v;
  }
  __syncthreads();

  const int cg = tid & 7;
  const int rg = tid >> 3;
  const int M = (rg & 15) << 2;
  const int cb = cg << 3;

  float4 A00 = make_float4(0.f, 0.f, 0.f, 0.f), A01 = A00;
  float4 A10 = A00, A11 = A00, A20 = A00, A21 = A00, A30 = A00, A31 = A00;

#pragma unroll 4
  for (int k = 0; k < D; ++k) {
    const float4 w0 = *(const float4*)&ws[k * D + cb];
    const float4 w1 = *(const float4*)&ws[k * D + cb + 4];
    const int kk = k ^ M;
    const float x0 = xs[(rg * 4 + 0) * D + kk];
    const float x1 = xs[(rg * 4 + 1) * D + kk];
    const float x2 = xs[(rg * 4 + 2) * D + kk];
    const float x3 = xs[(rg * 4 + 3) * D + kk];
    A00.x = fmaf(w0.x, x0, A00.x); A00.y = fmaf(w0.y, x0, A00.y);
    A00.z = fmaf(w0.z, x0, A00.z); A00.w = fmaf(w0.w, x0, A00.w);
    A01.x = fmaf(w1.x, x0, A01.x); A01.y = fmaf(w1.y, x0, A01.y);
    A01.z = fmaf(w1.z, x0, A01.z); A01.w = fmaf(w1.w, x0, A01.w);
    A10.x = fmaf(w0.x, x1, A10.x); A10.y = fmaf(w0.y, x1, A10.y);
    A10.z = fmaf(w0.z, x1, A10.z); A10.w = fmaf(w0.w, x1, A10.w);
    A11.x = fmaf(w1.x, x1, A11.x); A11.y = fmaf(w1.y, x1, A11.y);
    A11.z = fmaf(w1.z, x1, A11.z); A11.w = fmaf(w1.w, x1, A11.w);
    A20.x = fmaf(w0.x, x2, A20.x); A20.y = fmaf(w0.y, x2, A20.y);
    A20.z = fmaf(w0.z, x2, A20.z); A20.w = fmaf(w0.w, x2, A20.w);
    A21.x = fmaf(w1.x, x2, A21.x); A21.y = fmaf(w1.y, x2, A21.y);
    A21.z = fmaf(w1.z, x2, A21.z); A21.w = fmaf(w1.w, x2, A21.w);
    A30.x = fmaf(w0.x, x3, A30.x); A30.y = fmaf(w0.y, x3, A30.y);
    A30.z = fmaf(w0.z, x3, A30.z); A30.w = fmaf(w0.w, x3, A30.w);
    A31.x = fmaf(w1.x, x3, A31.x); A31.y = fmaf(w1.y, x3, A31.y);
    A31.z = fmaf(w1.z, x3, A31.z); A31.w = fmaf(w1.w, x3, A31.w);
  }

#define STORE_ROW(i, L, R)                                          \
  {                                                                 \
    const int r = rowBase + rg * 4 + (i);                           \
    if (r < N) {                                                    \
      __half2 h[4];                                                 \
      h[0] = __floats2half2_rn((L).x, (L).y);                       \
      h[1] = __floats2half2_rn((L).z, (L).w);                       \
      h[2] = __floats2half2_rn((R).x, (R).y);                       \
      h[3] = __floats2half2_rn((R).z, (R).w);                       \
      *(float4*)&sup[(size_t)r * D + cb] = *(float4*)h;             \
    }                                                               \
  }
  STORE_ROW(0, A00, A01)
  STORE_ROW(1, A10, A11)
  STORE_ROW(2, A20, A21)
  STORE_ROW(3, A30, A31)
#undef STORE_ROW
}

// ---------------------------------------------------------------------------
// Kernel 2: out[r,:] = relu( sum_{e in row r} val[e] * sup[col[e],:] )
// One wave per TWO consecutive rows, software-pipelined: both rows' metadata
// loads issue up front, then both rows' gathers, THEN row 0 is consumed
// (row 1's gathers stay in flight across the vmcnt wait) — keeps ~2x more
// L2 misses outstanding per wave vs the per-row structure.
// 8 lanes per edge, float4 (16B = 8 fp16 cols) gathers; zero-pad to slot
// count; 3-level shfl_xor reduce; lanes 0-7 store with fused ReLU.
// ---------------------------------------------------------------------------

#define DECL_ACC(p)                                                   \
  float p##_0 = 0.f, p##_1 = 0.f, p##_2 = 0.f, p##_3 = 0.f,           \
        p##_4 = 0.f, p##_5 = 0.f, p##_6 = 0.f, p##_7 = 0.f;

#define ACCUM(p, Q, V)                                                \
  {                                                                   \
    const __half2* h_ = (const __half2*)&(Q);                         \
    const float2 f0_ = __half22float2(h_[0]);                         \
    const float2 f1_ = __half22float2(h_[1]);                         \
    const float2 f2_ = __half22float2(h_[2]);                         \
    const float2 f3_ = __half22float2(h_[3]);                         \
    p##_0 = fmaf(f0_.x, (V), p##_0); p##_1 = fmaf(f0_.y, (V), p##_1); \
    p##_2 = fmaf(f1_.x, (V), p##_2); p##_3 = fmaf(f1_.y, (V), p##_3); \
    p##_4 = fmaf(f2_.x, (V), p##_4); p##_5 = fmaf(f2_.y, (V), p##_5); \
    p##_6 = fmaf(f3_.x, (V), p##_6); p##_7 = fmaf(f3_.y, (V), p##_7); \
  }

#define REDUCE_STORE(p, r)                                            \
  {                                                                   \
    p##_0 += __shfl_xor(p##_0, 8);  p##_0 += __shfl_xor(p##_0, 16);   \
    p##_0 += __shfl_xor(p##_0, 32);                                   \
    p##_1 += __shfl_xor(p##_1, 8);  p##_1 += __shfl_xor(p##_1, 16);   \
    p##_1 += __shfl_xor(p##_1, 32);                                   \
    p##_2 += __shfl_xor(p##_2, 8);  p##_2 += __shfl_xor(p##_2, 16);   \
    p##_2 += __shfl_xor(p##_2, 32);                                   \
    p##_3 += __shfl_xor(p##_3, 8);  p##_3 += __shfl_xor(p##_3, 16);   \
    p##_3 += __shfl_xor(p##_3, 32);                                   \
    p##_4 += __shfl_xor(p##_4, 8);  p##_4 += __shfl_xor(p##_4, 16);   \
    p##_4 += __shfl_xor(p##_4, 32);                                   \
    p##_5 += __shfl_xor(p##_5, 8);  p##_5 += __shfl_xor(p##_5, 16);   \
    p##_5 += __shfl_xor(p##_5, 32);                                   \
    p##_6 += __shfl_xor(p##_6, 8);  p##_6 += __shfl_xor(p##_6, 16);   \
    p##_6 += __shfl_xor(p##_6, 32);                                   \
    p##_7 += __shfl_xor(p##_7, 8);  p##_7 += __shfl_xor(p##_7, 16);   \
    p##_7 += __shfl_xor(p##_7, 32);                                   \
    if (g == 0) {                                                     \
      float4 o0, o1;                                                  \
      o0.x = fmaxf(p##_0, 0.f); o0.y = fmaxf(p##_1, 0.f);             \
      o0.z = fmaxf(p##_2, 0.f); o0.w = fmaxf(p##_3, 0.f);             \
      o1.x = fmaxf(p##_4, 0.f); o1.y = fmaxf(p##_5, 0.f);             \
      o1.z = fmaxf(p##_6, 0.f); o1.w = fmaxf(p##_7, 0.f);             \
      float* po = &out[(size_t)(r)*D + lg * 8];                       \
      *(float4*)po = o0;                                              \
      *(float4*)(po + 4) = o1;                                        \
    }                                                                 \
  }

#define ROW_GENERAL(r, s, deg, myc, myv)                              \
  {                                                                   \
    DECL_ACC(t)                                                       \
    const int K = (deg) < 64 ? (deg) : 64;                            \
    for (int jb = 0; jb < K; jb += 16) {                              \
      const int j0 = jb + g, j1 = jb + 8 + g;                         \
      int c0 = __shfl((myc), j0); float v0 = __shfl((myv), j0);       \
      int c1 = __shfl((myc), j1); float v1 = __shfl((myv), j1);       \
      if (j0 >= K) { c0 = 0; v0 = 0.f; }                              \
      if (j1 >= K) { c1 = 0; v1 = 0.f; }                              \
      const float4 q0 = sup4[(size_t)c0 * 8 + lg];                    \
      const float4 q1 = sup4[(size_t)c1 * 8 + lg];                    \
      ACCUM(t, q0, v0)                                                \
      ACCUM(t, q1, v1)                                                \
    }                                                                 \
    for (int j = 64; j < (deg); j += 8) {                             \
      int c = 0; float v = 0.f;                                       \
      if (j + g < (deg)) { c = col[(s) + j + g]; v = val[(s) + j + g]; } \
      const float4 q = sup4[(size_t)c * 8 + lg];                      \
      ACCUM(t, q, v)                                                  \
    }                                                                 \
    REDUCE_STORE(t, r)                                                \
  }

__global__ __launch_bounds__(256) void spmm_relu(
    const float4* __restrict__ sup4,  // fp16 rows: 8 float4 per row
    const int* __restrict__ rp, const int* __restrict__ col,
    const float* __restrict__ val, float* __restrict__ out, int N) {
  const int lane = threadIdx.x & 63;
  const int g = lane >> 3;  // edge slot (0..7)
  const int lg = lane & 7;  // column slice: cols 8*lg .. 8*lg+7
  const int r0 = (blockIdx.x * 4 + (threadIdx.x >> 6)) * 2;
  if (r0 >= N) return;
  const int r1 = r0 + 1;
  const bool has1 = r1 < N;

  const int s0 = __builtin_amdgcn_readfirstlane(rp[r0]);
  const int e0 = __builtin_amdgcn_readfirstlane(rp[r0 + 1]);
  int e1 = e0;
  if (has1) e1 = __builtin_amdgcn_readfirstlane(rp[r0 + 2]);
  const int s1 = e0;
  const int deg0 = e0 - s0;
  const int deg1 = e1 - s1;

  // Metadata prefetch for BOTH rows — 4 independent coalesced loads in flight.
  int myc0 = 0, myc1 = 0;
  float myv0 = 0.f, myv1 = 0.f;
  if (lane < deg0) { myc0 = col[s0 + lane]; myv0 = val[s0 + lane]; }
  if (lane < deg1) { myc1 = col[s1 + lane]; myv1 = val[s1 + lane]; }

  if (deg0 <= 16 && deg1 <= 16 && has1) {
    // Fast path (~80% of row pairs): all 4 gather instructions issue
    // back-to-back before any consumption — both rows' misses overlap.
    const int j0 = g, j1 = 8 + g;
    int c00 = __shfl(myc0, j0); float v00 = __shfl(myv0, j0);
    int c01 = __shfl(myc0, j1); float v01 = __shfl(myv0, j1);
    int c10 = __shfl(myc1, j0); float v10 = __shfl(myv1, j0);
    int c11 = __shfl(myc1, j1); float v11 = __shfl(myv1, j1);
    if (j0 >= deg0) { c00 = 0; v00 = 0.f; }
    if (j1 >= deg0) { c01 = 0; v01 = 0.f; }
    if (j0 >= deg1) { c10 = 0; v10 = 0.f; }
    if (j1 >= deg1) { c11 = 0; v11 = 0.f; }
    const float4 q00 = sup4[(size_t)c00 * 8 + lg];
    const float4 q01 = sup4[(size_t)c01 * 8 + lg];
    const float4 q10 = sup4[(size_t)c10 * 8 + lg];
    const float4 q11 = sup4[(size_t)c11 * 8 + lg];
    {
      DECL_ACC(a)
      ACCUM(a, q00, v00)
      ACCUM(a, q01, v01)
      REDUCE_STORE(a, r0)
    }
    {
      DECL_ACC(b)
      ACCUM(b, q10, v10)
      ACCUM(b, q11, v11)
      REDUCE_STORE(b, r1)
    }
    return;
  }

  // General path: rows processed sequentially (round-4 structure).
  ROW_GENERAL(r0, s0, deg0, myc0, myv0)
  if (has1) ROW_GENERAL(r1, s1, deg1, myc1, myv1)
}

#undef ROW_GENERAL
#undef REDUCE_STORE
#undef ACCUM
#undef DECL_ACC

// ---------------------------------------------------------------------------
extern "C" void kernel_launch(void* const* d_in, const int* in_sizes, int n_in,
                              void* d_out, int out_size, void* d_ws, size_t ws_size,
                              hipStream_t stream) {
  const float* x = (const float*)d_in[0];
  const float* w = (const float*)d_in[1];
  const int* erow = (const int*)d_in[2];
  const int* ecol = (const int*)d_in[3];
  const float* eval = (const float*)d_in[4];
  float* out = (float*)d_out;

  const int N = in_sizes[0] / D;  // 100000
  const int E = in_sizes[2];      // 1200000

  __half* sup = (__half*)d_ws;  // N*64 fp16 = 12.8 MB
  int* rp = (int*)((char*)d_ws + (((size_t)N * D * sizeof(__half) + 255) & ~(size_t)255));

  const int nGemmBlocks = (N + 127) / 128;
  const int nRpBlocks = (E + 255) / 256;

  gemm_and_rowptr<<<nGemmBlocks + nRpBlocks, 256, 0, stream>>>(
      x, w, sup, N, erow, rp, E, nGemmBlocks);
  spmm_relu<<<(N + 7) / 8, 256, 0, stream>>>((const float4*)sup, rp, ecol, eval,
                                             out, N);
}